// Round 11
// baseline (105.326 us; speedup 1.0000x reference)
//
#include <hip/hip_runtime.h>

#define WW 512
#define HH 256
#define TS 48
#define NB 2
#define ZS 32                // z-rows marched per wave
#define KAPPA 0.01f
#define NU 0.01f

#define ROW(zz) (min(max((zz), 0), HH - 1) * WW)
#define LD4(p) (*reinterpret_cast<const float4*>(p))
#define LD2(p) (*reinterpret_cast<const float2*>(p))

__device__ __forceinline__ float elem(const float4 v, int e) {
    return e == 0 ? v.x : e == 1 ? v.y : e == 2 ? v.z : v.w;
}
__device__ __forceinline__ float4 f4add(const float4 a, const float4 b) {
    return make_float4(a.x + b.x, a.y + b.y, a.z + b.z, a.w + b.w);
}

// jnp.gradient first+second (gradient-of-gradient) along one axis, index i of n.
__device__ __forceinline__ void grad12(float fm2, float fm1, float fc, float fp1, float fp2,
                                       int i, int n, float invh, float& g, float& gg) {
    const float half = 0.5f * invh;
    if (i == 0) {
        g = (fp1 - fc) * invh;
        float g1 = (fp2 - fc) * half;
        gg = (g1 - g) * invh;
    } else if (i == n - 1) {
        g = (fc - fm1) * invh;
        float gm = (fc - fm2) * half;
        gg = (g - gm) * invh;
    } else {
        g = (fp1 - fm1) * half;
        float gim = (i == 1)     ? (fc - fm1) * invh : (fc - fm2) * half;
        float gip = (i == n - 2) ? (fp1 - fc) * invh : (fp2 - fc) * half;
        gg = (gip - gim) * half;
    }
}

__device__ __forceinline__ float grad1(float fm1, float fc, float fp1, int i, int n, float invh) {
    if (i == 0)     return (fp1 - fc) * invh;
    if (i == n - 1) return (fc - fm1) * invh;
    return (fp1 - fm1) * (0.5f * invh);
}

// 1536 blocks x 64 threads (one wave per block, no barriers).
// XCD group g = bi&7 encodes (b, xh, t-half): each XCD works one x-half of one
// batch over 24 consecutive t-planes, all marching z together -> every
// z-stencil value lives in registers; t+-1 center rows are L2-warm (mutual
// pre-warming by neighbor-t blocks; live window ~2-4 MB per XCD).
__global__ __launch_bounds__(64) void rbc_loss_kernel(const float* __restrict__ pred,
                                                      double* __restrict__ dacc) {
    const int sT = HH * WW;          // 131072
    const int sC = TS * sT;
    const int sB = 5 * sC;

    const int bi = blockIdx.x;
    const int g     = bi & 7;        // XCD (hardware round-robins bi % 8)
    const int local = bi >> 3;       // 0..191 within XCD
    const int b  = g >> 2;
    const int xh = (g >> 1) & 1;
    const int th = g & 1;
    const int tt = local >> 3;       // 0..23
    const int zs = local & 7;        // 0..7
    const int t  = th * 24 + tt;
    const int z0 = zs * ZS;

    const int lane = threadIdx.x;            // 64-thread block = one wave
    const int x0 = (xh << 8) + (lane << 2);  // quad base

    const float invdt = TS / 10.0f;
    const float invdx = (float)(WW / 6.283185307179586);
    const float invdz = HH / 2.0f;

    const float* __restrict__ pT = pred + (size_t)b * sB + 0 * (size_t)sC;
    const float* __restrict__ pU = pred + (size_t)b * sB + 1 * (size_t)sC;
    const float* __restrict__ pV = pred + (size_t)b * sB + 2 * (size_t)sC;
    const float* __restrict__ q3 = pred + (size_t)b * sB + 3 * (size_t)sC;
    const float* __restrict__ q4 = pred + (size_t)b * sB + 4 * (size_t)sC;

    const size_t o = (size_t)t * sT;
    // t-clamped neighbor-plane bases (block-uniform)
    const float* __restrict__ pTm = pT + o - (t > 0      ? (size_t)sT : 0);
    const float* __restrict__ pTp = pT + o + (t < TS - 1 ? (size_t)sT : 0);
    const float* __restrict__ pUm = pU + o - (t > 0      ? (size_t)sT : 0);
    const float* __restrict__ pUp = pU + o + (t < TS - 1 ? (size_t)sT : 0);
    const float* __restrict__ pVm = pV + o - (t > 0      ? (size_t)sT : 0);
    const float* __restrict__ pVp = pV + o + (t < TS - 1 ? (size_t)sT : 0);

    // seam between x-halves (x=255|256); global x-edges handled by grad12 branches
    const bool isR = (lane == 63) && (xh == 0);   // needs x=256,257
    const bool isL = (lane == 0)  && (xh == 1);   // needs x=254,255
    const int sOff  = isR ? 256 : 254;
    const int sPOff = isR ? 256 : 255;

    // ---- z-ring warm-up (clamped rows feed only grad12 edge branches) ----
    float4 Tzm2 = LD4(pT + o + ROW(z0 - 2) + x0), Tzm1 = LD4(pT + o + ROW(z0 - 1) + x0);
    float4 Tzc  = LD4(pT + o + ROW(z0)     + x0), Tzp1 = LD4(pT + o + ROW(z0 + 1) + x0);
    float4 Uzm2 = LD4(pU + o + ROW(z0 - 2) + x0), Uzm1 = LD4(pU + o + ROW(z0 - 1) + x0);
    float4 Uzc  = LD4(pU + o + ROW(z0)     + x0), Uzp1 = LD4(pU + o + ROW(z0 + 1) + x0);
    float4 Vzm2 = LD4(pV + o + ROW(z0 - 2) + x0), Vzm1 = LD4(pV + o + ROW(z0 - 1) + x0);
    float4 Vzc  = LD4(pV + o + ROW(z0)     + x0), Vzp1 = LD4(pV + o + ROW(z0 + 1) + x0);
    float4 Pm1 = f4add(LD4(q3 + o + ROW(z0 - 1) + x0), LD4(q4 + o + ROW(z0 - 1) + x0));
    float4 Pc  = f4add(LD4(q3 + o + ROW(z0)     + x0), LD4(q4 + o + ROW(z0)     + x0));

    float acc = 0.f;

    #pragma unroll 1
    for (int z = z0; z < z0 + ZS; ++z) {
        const int rowC = z * WW;
        const int rP1 = ROW(z + 1), rP2 = ROW(z + 2);

        // ---- loads in consumption order ----
        float4 B3  = LD4(q3 + o + rP1 + x0);            // P ring advance
        float4 B4  = LD4(q4 + o + rP1 + x0);
        float4 TzI = LD4(pT + o + rP2 + x0);            // T/U/V ring advance
        float4 UzI = LD4(pU + o + rP2 + x0);
        float4 VzI = LD4(pV + o + rP2 + x0);
        float2 Tse = make_float2(0.f, 0.f), Use = Tse, Vse = Tse; float Pse = 0.f;
        if (isR | isL) {                                 // seam (2 lanes, masked)
            Tse = LD2(pT + o + rowC + sOff);
            Use = LD2(pU + o + rowC + sOff);
            Vse = LD2(pV + o + rowC + sOff);
            Pse = q3[o + rowC + sPOff] + q4[o + rowC + sPOff];
        }
        float4 Ttm = LD4(pTm + rowC + x0), Ttp = LD4(pTp + rowC + x0);  // t+-1
        float4 Utm = LD4(pUm + rowC + x0), Utp = LD4(pUp + rowC + x0);
        float4 Vtm = LD4(pVm + rowC + x0), Vtp = LD4(pVp + rowC + x0);

        float4 Pp1 = f4add(B3, B4);

        // x-neighbors from ring registers via shuffles (no memory wait)
        float Tl2 = __shfl_up(Tzc.z, 1),   Tl3 = __shfl_up(Tzc.w, 1);
        float Tr0 = __shfl_down(Tzc.x, 1), Tr1 = __shfl_down(Tzc.y, 1);
        float Ul2 = __shfl_up(Uzc.z, 1),   Ul3 = __shfl_up(Uzc.w, 1);
        float Ur0 = __shfl_down(Uzc.x, 1), Ur1 = __shfl_down(Uzc.y, 1);
        float Vl2 = __shfl_up(Vzc.z, 1),   Vl3 = __shfl_up(Vzc.w, 1);
        float Vr0 = __shfl_down(Vzc.x, 1), Vr1 = __shfl_down(Vzc.y, 1);
        float Pl3 = __shfl_up(Pc.w, 1),    Pr0 = __shfl_down(Pc.x, 1);

        if (isR) { Tr0 = Tse.x; Tr1 = Tse.y; Ur0 = Use.x; Ur1 = Use.y;
                   Vr0 = Vse.x; Vr1 = Vse.y; Pr0 = Pse; }
        if (isL) { Tl2 = Tse.x; Tl3 = Tse.y; Ul2 = Use.x; Ul3 = Use.y;
                   Vl2 = Vse.x; Vl3 = Vse.y; Pl3 = Pse; }

        #pragma unroll
        for (int e = 0; e < 4; ++e) {
            const int i = x0 + e;
            const float txm2 = e == 0 ? Tl2 : e == 1 ? Tl3 : elem(Tzc, e - 2);
            const float txm1 = e == 0 ? Tl3 : elem(Tzc, e - 1);
            const float txc  = elem(Tzc, e);
            const float txp1 = e == 3 ? Tr0 : elem(Tzc, e + 1);
            const float txp2 = e == 2 ? Tr0 : e == 3 ? Tr1 : elem(Tzc, e + 2);
            const float uxm2 = e == 0 ? Ul2 : e == 1 ? Ul3 : elem(Uzc, e - 2);
            const float uxm1 = e == 0 ? Ul3 : elem(Uzc, e - 1);
            const float uxc  = elem(Uzc, e);
            const float uxp1 = e == 3 ? Ur0 : elem(Uzc, e + 1);
            const float uxp2 = e == 2 ? Ur0 : e == 3 ? Ur1 : elem(Uzc, e + 2);
            const float vxm2 = e == 0 ? Vl2 : e == 1 ? Vl3 : elem(Vzc, e - 2);
            const float vxm1 = e == 0 ? Vl3 : elem(Vzc, e - 1);
            const float vxc  = elem(Vzc, e);
            const float vxp1 = e == 3 ? Vr0 : elem(Vzc, e + 1);
            const float vxp2 = e == 2 ? Vr0 : e == 3 ? Vr1 : elem(Vzc, e + 2);
            const float pxm1 = e == 0 ? Pl3 : elem(Pc, e - 1);
            const float pxc  = elem(Pc, e);
            const float pxp1 = e == 3 ? Pr0 : elem(Pc, e + 1);

            // x-grads first (ring regs only), then P, z (ring), dt (loads)
            float dTdx, dTdxx, dTdz, dTdzz;
            grad12(txm2, txm1, txc, txp1, txp2, i, WW, invdx, dTdx, dTdxx);
            float dUdx, dUdxx, dUdz, dUdzz;
            grad12(uxm2, uxm1, uxc, uxp1, uxp2, i, WW, invdx, dUdx, dUdxx);
            float dVdx, dVdxx, dVdz, dVdzz;
            grad12(vxm2, vxm1, vxc, vxp1, vxp2, i, WW, invdx, dVdx, dVdxx);

            float dPdx = grad1(pxm1, pxc, pxp1, i, WW, invdx);
            float dPdz = grad1(elem(Pm1, e), pxc, elem(Pp1, e), z, HH, invdz);

            grad12(elem(Tzm2, e), elem(Tzm1, e), txc, elem(Tzp1, e), elem(TzI, e), z, HH, invdz, dTdz, dTdzz);
            grad12(elem(Uzm2, e), elem(Uzm1, e), uxc, elem(Uzp1, e), elem(UzI, e), z, HH, invdz, dUdz, dUdzz);
            grad12(elem(Vzm2, e), elem(Vzm1, e), vxc, elem(Vzp1, e), elem(VzI, e), z, HH, invdz, dVdz, dVdzz);

            float dTdt, dUdt, dVdt;   // t is block-uniform
            if (t == 0) {
                dTdt = (elem(Ttp, e) - txc) * invdt;
                dUdt = (elem(Utp, e) - uxc) * invdt;
                dVdt = (elem(Vtp, e) - vxc) * invdt;
            } else if (t == TS - 1) {
                dTdt = (txc - elem(Ttm, e)) * invdt;
                dUdt = (uxc - elem(Utm, e)) * invdt;
                dVdt = (vxc - elem(Vtm, e)) * invdt;
            } else {
                dTdt = (elem(Ttp, e) - elem(Ttm, e)) * (0.5f * invdt);
                dUdt = (elem(Utp, e) - elem(Utm, e)) * (0.5f * invdt);
                dVdt = (elem(Vtp, e) - elem(Vtm, e)) * (0.5f * invdt);
            }

            float dv = dUdx + dVdz;
            float te = dTdt + uxc * dTdx + vxc * dTdz - KAPPA * (dTdxx + dTdzz);
            float xm = dUdt + uxc * dUdx + vxc * dUdz + dPdx - NU * (dUdxx + dUdzz);
            float zm = dVdt + uxc * dVdx + vxc * dVdz + dPdz - NU * (dVdxx + dVdzz) - txc;

            acc += dv * dv + te * te + xm * xm + zm * zm;
        }

        // shift rings
        Tzm2 = Tzm1; Tzm1 = Tzc; Tzc = Tzp1; Tzp1 = TzI;
        Uzm2 = Uzm1; Uzm1 = Uzc; Uzc = Uzp1; Uzp1 = UzI;
        Vzm2 = Vzm1; Vzm1 = Vzc; Vzc = Vzp1; Vzp1 = VzI;
        Pm1 = Pc; Pc = Pp1;
    }

    // single-wave block: shuffle reduce + one atomic, no LDS/barrier
    #pragma unroll
    for (int off = 32; off; off >>= 1) acc += __shfl_down(acc, off, 64);
    if (lane == 0) atomicAdd(dacc, (double)acc);
}

__global__ void rbc_finalize(const double* __restrict__ dacc, float* __restrict__ out) {
    const double N = (double)NB * TS * HH * WW;   // 12,582,912
    out[0] = (float)(dacc[0] / N);
}

extern "C" void kernel_launch(void* const* d_in, const int* in_sizes, int n_in,
                              void* d_out, int out_size, void* d_ws, size_t ws_size,
                              hipStream_t stream) {
    const float* pred = (const float*)d_in[0];
    double* dacc = (double*)d_ws;
    hipMemsetAsync(dacc, 0, sizeof(double), stream);

    const int nblocks = 8 * 24 * 8;   // 1536 one-wave blocks (6 waves/CU)
    rbc_loss_kernel<<<nblocks, 64, 0, stream>>>(pred, dacc);
    rbc_finalize<<<1, 1, 0, stream>>>(dacc, (float*)d_out);
}